// Round 4
// baseline (82.238 us; speedup 1.0000x reference)
//
#include <hip/hip_runtime.h>

// Problem constants (B=64, IN=1024, UNITS=1024, BITS=8)
#define IN_F   1024
#define UNITS  1024
#define BDIM   64
#define BG     4            // b per block          (16 b-groups)
#define JT     256          // j per block          (4 j-tiles)
#define ICH    8            // i-chunks (cross-block split-K)
#define CHUNK  128          // IN_F / ICH
#define REPS   4            // in-block i sub-split (LDS-reduced)
#define ISUB   32           // CHUNK / REPS
// grid = 16 * 4 * 8 = 512 blocks; bg = bid&15, jt = (bid>>4)&3, ic = bid>>6

// Math: out[b,j] = relu(bias[j] + sum_i trunc(x[b,i] * K[i,j] / 256))
// Exact collapse of the reference's 4-round base-4 digit loop:
//   floor((floor(A/4)+B)/4) = floor((A+4B)/16) applied 4x; trunc is
//   odd-symmetric in sign(w), x >= 0. All intermediates are exact small
//   integers in fp32 -> bit-exact, order-independent (atomics safe).

__global__ __launch_bounds__(256) void zero_ws_kernel(float4* __restrict__ ws4)
{
    const int idx = blockIdx.x * 256 + threadIdx.x;   // 64 blocks -> 16384 f4
    ws4[idx] = make_float4(0.f, 0.f, 0.f, 0.f);
}

__global__ __launch_bounds__(256) void partial_kernel(
    const float* __restrict__ x, const float* __restrict__ K,
    float* __restrict__ ws)
{
    const int bid = blockIdx.x;            // 512 blocks
    const int bg = bid & 15;
    const int jt = (bid >> 4) & 3;
    const int ic = bid >> 6;
    const int t  = threadIdx.x;
    const int b0 = bg * BG;
    const int j0 = jt * JT;
    const int i0 = ic * CHUNK;

    const int j4  = t & 63;                // 64 float4 j-groups per block
    const int rep = t >> 6;                // 4 i-sub-reps

    // x tile [i][b], pre-scaled by 1/256
    __shared__ float xs[CHUNK * BG];       // 512 floats
    {
        const int t2 = t;                  // two elements per thread
        const int ii0 = t2 >> 2, bb0 = t2 & 3;
        xs[ii0 * BG + bb0] = x[(b0 + bb0) * IN_F + i0 + ii0] * (1.0f / 256.0f);
        const int t3 = t + 256;
        const int ii1 = t3 >> 2, bb1 = t3 & 3;
        xs[ii1 * BG + bb1] = x[(b0 + bb1) * IN_F + i0 + ii1] * (1.0f / 256.0f);
    }
    __syncthreads();

    float4 acc0 = make_float4(0.f, 0.f, 0.f, 0.f);
    float4 acc1 = acc0, acc2 = acc0, acc3 = acc0;

    const int ib = rep * ISUB;             // this rep's i-range within chunk
    const float4* kp = (const float4*)(K + (size_t)(i0 + ib) * UNITS + j0) + j4;
#pragma unroll 8
    for (int r = 0; r < ISUB; ++r) {
        const float4 k4 = kp[(size_t)r * (UNITS / 4)];        // coalesced dwordx4
        const float4 xv = *(const float4*)&xs[(ib + r) * BG]; // broadcast
        acc0.x += truncf(xv.x * k4.x); acc0.y += truncf(xv.x * k4.y);
        acc0.z += truncf(xv.x * k4.z); acc0.w += truncf(xv.x * k4.w);
        acc1.x += truncf(xv.y * k4.x); acc1.y += truncf(xv.y * k4.y);
        acc1.z += truncf(xv.y * k4.z); acc1.w += truncf(xv.y * k4.w);
        acc2.x += truncf(xv.z * k4.x); acc2.y += truncf(xv.z * k4.y);
        acc2.z += truncf(xv.z * k4.z); acc2.w += truncf(xv.z * k4.w);
        acc3.x += truncf(xv.w * k4.x); acc3.y += truncf(xv.w * k4.y);
        acc3.z += truncf(xv.w * k4.z); acc3.w += truncf(xv.w * k4.w);
    }

    // in-block reduction across the 4 reps
    __shared__ float red[REPS * BG * JT];  // 4*1024 floats = 16 KB
    float* rb = red + rep * (BG * JT);
    *(float4*)&rb[(0 * 64 + j4) * 4] = acc0;
    *(float4*)&rb[(1 * 64 + j4) * 4] = acc1;
    *(float4*)&rb[(2 * 64 + j4) * 4] = acc2;
    *(float4*)&rb[(3 * 64 + j4) * 4] = acc3;
    __syncthreads();

    // thread u sums 4 consecutive floats over reps, atomically accumulates
    const float4 s0 = *(const float4*)&red[0 * 1024 + t * 4];
    const float4 s1 = *(const float4*)&red[1 * 1024 + t * 4];
    const float4 s2 = *(const float4*)&red[2 * 1024 + t * 4];
    const float4 s3 = *(const float4*)&red[3 * 1024 + t * 4];
    const float sx = s0.x + s1.x + s2.x + s3.x;
    const float sy = s0.y + s1.y + s2.y + s3.y;
    const float sz = s0.z + s1.z + s2.z + s3.z;
    const float sw = s0.w + s1.w + s2.w + s3.w;

    const int bb = t >> 6;                 // output decode: t*4 = (bb*64+jj)*4
    const int jj = t & 63;
    float* wp = ws + (size_t)(b0 + bb) * UNITS + j0 + jj * 4;
    atomicAdd(wp + 0, sx);
    atomicAdd(wp + 1, sy);
    atomicAdd(wp + 2, sz);
    atomicAdd(wp + 3, sw);
}

__global__ __launch_bounds__(256) void finalize_kernel(
    const float4* __restrict__ ws4, const float4* __restrict__ bias4,
    float4* __restrict__ out4)
{
    const int idx = blockIdx.x * 256 + threadIdx.x;  // 64 blocks -> 16384 f4
    const int j4 = idx & 255;                        // 256 f4 per j-row
    const float4 s = ws4[idx];
    const float4 bv = bias4[j4];
    float4 r;
    r.x = fmaxf(s.x + bv.x, 0.f);
    r.y = fmaxf(s.y + bv.y, 0.f);
    r.z = fmaxf(s.z + bv.z, 0.f);
    r.w = fmaxf(s.w + bv.w, 0.f);
    out4[idx] = r;
}

extern "C" void kernel_launch(void* const* d_in, const int* in_sizes, int n_in,
                              void* d_out, int out_size, void* d_ws, size_t ws_size,
                              hipStream_t stream) {
    const float* x    = (const float*)d_in[0];  // (64, 1024)
    const float* K    = (const float*)d_in[1];  // (1024, 1024)
    const float* bias = (const float*)d_in[2];  // (1024,)
    // d_in[3] = bits (always 8)
    float* out = (float*)d_out;                 // (64, 1024)
    float* ws  = (float*)d_ws;                  // uses B*UNITS*4 = 256 KB

    zero_ws_kernel<<<64, 256, 0, stream>>>((float4*)ws);
    partial_kernel<<<512, 256, 0, stream>>>(x, K, ws);
    finalize_kernel<<<64, 256, 0, stream>>>((const float4*)ws,
                                            (const float4*)bias, (float4*)out);
}

// Round 5
// 76.680 us; speedup vs baseline: 1.0725x; 1.0725x over previous
//
#include <hip/hip_runtime.h>

// Problem constants (B=64, IN=1024, UNITS=1024, BITS=8)
#define IN_F   1024
#define UNITS  1024
#define BDIM   64
#define BG     4            // b per block   (16 b-groups)
#define JT     32           // j per block   (32 j-tiles)
#define NBG    16           // BDIM / BG
#define NJT    32           // UNITS / JT
#define REPS   32           // in-block i-splits
#define ISUB   32           // IN_F / REPS
// grid = NBG * NJT = 512 blocks, 256 threads, ONE kernel, no workspace.

// Math: out[b,j] = relu(bias[j] + sum_i trunc(x[b,i] * K[i,j] / 256))
// Exact collapse of the reference's 4-round base-4 digit loop:
//   floor((floor(A/4)+B)/4) = floor((A+4B)/16) applied 4x; trunc is
//   odd-symmetric in sign(w), x >= 0. All intermediates are exact small
//   integers in fp32 -> bit-exact, any summation order is identical.

__global__ __launch_bounds__(256) void dense_kernel(
    const float* __restrict__ x, const float* __restrict__ K,
    const float* __restrict__ bias, float* __restrict__ out)
{
    const int bid = blockIdx.x;          // 512 blocks
    const int bg = bid & (NBG - 1);      // 16 b-groups
    const int jt = bid >> 4;             // 32 j-tiles
    const int t  = threadIdx.x;
    const int b0 = bg * BG;
    const int j0 = jt * JT;

    // full-K x tile [i][b], pre-scaled by 1/256   (16 KB)
    __shared__ float xs[IN_F * BG];
#pragma unroll
    for (int c = 0; c < 16; ++c) {
        const int e  = c * 256 + t;      // 4096 elements, coalesced along i
        const int bb = e >> 10;
        const int ii = e & 1023;
        xs[ii * BG + bb] = x[(b0 + bb) * IN_F + ii] * (1.0f / 256.0f);
    }
    __syncthreads();

    const int j4  = t & 7;               // 8 float4 j-groups = 32 j
    const int rep = t >> 3;              // 32 i-reps of 32

    float4 a0 = make_float4(0.f, 0.f, 0.f, 0.f);
    float4 a1 = a0, a2 = a0, a3 = a0;

    const float4* kp = (const float4*)(K + (size_t)(rep * ISUB) * UNITS + j0) + j4;
    const float*  xp = xs + (rep * ISUB) * BG;
#pragma unroll 8
    for (int r = 0; r < ISUB; ++r) {
        const float4 k4 = kp[(size_t)r * (UNITS / 4)];   // coalesced dwordx4 (L2)
        const float4 xv = *(const float4*)&xp[r * BG];   // 8-lane broadcast b128
        a0.x += truncf(xv.x * k4.x); a0.y += truncf(xv.x * k4.y);
        a0.z += truncf(xv.x * k4.z); a0.w += truncf(xv.x * k4.w);
        a1.x += truncf(xv.y * k4.x); a1.y += truncf(xv.y * k4.y);
        a1.z += truncf(xv.y * k4.z); a1.w += truncf(xv.y * k4.w);
        a2.x += truncf(xv.z * k4.x); a2.y += truncf(xv.z * k4.y);
        a2.z += truncf(xv.z * k4.z); a2.w += truncf(xv.z * k4.w);
        a3.x += truncf(xv.w * k4.x); a3.y += truncf(xv.w * k4.y);
        a3.z += truncf(xv.w * k4.z); a3.w += truncf(xv.w * k4.w);
    }

    // in-block reduction over the 32 reps: red[rep][b*JT + j]   (16 KB)
    __shared__ float red[REPS][BG * JT];
    {
        float* rb = red[rep];
        *(float4*)&rb[0 * JT + j4 * 4] = a0;
        *(float4*)&rb[1 * JT + j4 * 4] = a1;
        *(float4*)&rb[2 * JT + j4 * 4] = a2;
        *(float4*)&rb[3 * JT + j4 * 4] = a3;
    }
    __syncthreads();

    // 128 outputs per block; threads 0..127 finalize one each
    if (t < BG * JT) {
        float s = 0.f;
#pragma unroll
        for (int rp = 0; rp < REPS; ++rp) s += red[rp][t];   // 2-way max, free
        const int bb = t >> 5;           // t = bb*32 + jj
        const int jj = t & 31;
        const float v = s + bias[j0 + jj];
        out[(size_t)(b0 + bb) * UNITS + j0 + jj] = fmaxf(v, 0.f);
    }
}

extern "C" void kernel_launch(void* const* d_in, const int* in_sizes, int n_in,
                              void* d_out, int out_size, void* d_ws, size_t ws_size,
                              hipStream_t stream) {
    const float* x    = (const float*)d_in[0];  // (64, 1024)
    const float* K    = (const float*)d_in[1];  // (1024, 1024)
    const float* bias = (const float*)d_in[2];  // (1024,)
    // d_in[3] = bits (always 8)
    float* out = (float*)d_out;                 // (64, 1024)
    (void)d_ws; (void)ws_size;                  // no workspace needed

    dense_kernel<<<NBG * NJT, 256, 0, stream>>>(x, K, bias, out);
}

// Round 6
// 73.314 us; speedup vs baseline: 1.1217x; 1.0459x over previous
//
#include <hip/hip_runtime.h>

// Problem constants (B=64, IN=1024, UNITS=1024, BITS=8)
#define IN_F   1024
#define UNITS  1024
#define BDIM   64
#define NCH    8            // i-chunks (reduction split)
#define CHUNK  128          // IN_F / NCH
#define BG     4            // b-values per thread / per block

// Math: out[b,j] = relu(bias[j] + sum_i trunc(x[b,i] * K[i,j] / 256))
// Exact collapse of the reference's 4-round base-4 digit loop:
//   floor((floor(A/4)+B)/4) = floor((A+4B)/16) applied 4x; trunc is
//   odd-symmetric in sign(w), x >= 0. All intermediates are exact small
//   integers in fp32 -> bit-exact, order-independent.
//
// Structure notes (measured across R1..R5):
//  - wide j-tile => each wave's K load is one contiguous 256B/1KB request;
//    narrow j-tiles (R5) scatter to 8 segments/instr and cost +3 us.
//  - 2-kernel split-K via 2MB ws beats 1-kernel (76.7) and atomics (82.2).
//  - dur_us floor ~73 us is dominated by fixed harness tax (41 us ws-poison
//    fill visible in top-5 even when ws is unused, + restores + replay).

__global__ __launch_bounds__(256) void partial_kernel(
    const float* __restrict__ x, const float* __restrict__ K,
    float* __restrict__ ws)
{
    const int bid = blockIdx.x;          // 512 blocks
    const int jt = bid & 3;              // 4 j-tiles of 256
    const int bg = (bid >> 2) & 15;      // 16 b-groups of 4
    const int ic = bid >> 6;             // 8 i-chunks of 128
    const int tid = threadIdx.x;
    const int j  = jt * 256 + tid;
    const int b0 = bg * BG;
    const int i0 = ic * CHUNK;

    // x tile, pre-scaled by 1/256, transposed to [i][b] for ds_read_b128
    __shared__ float xs[CHUNK * BG];     // 512 floats = 2 KB
    for (int t = tid; t < CHUNK * BG; t += 256) {
        const int bb = t >> 7;           // 0..3
        const int ii = t & 127;          // 0..127 (coalesced along i)
        xs[ii * BG + bb] = x[(b0 + bb) * IN_F + i0 + ii] * (1.0f / 256.0f);
    }
    __syncthreads();

    float acc0 = 0.f, acc1 = 0.f, acc2 = 0.f, acc3 = 0.f;
    const float* kp = K + (size_t)i0 * UNITS + j;
#pragma unroll 8
    for (int i = 0; i < CHUNK; ++i) {
        const float k = kp[(size_t)i * UNITS];          // wave-contiguous dword
        const float4 xv = *(const float4*)&xs[i * BG];  // broadcast b128
        acc0 += truncf(xv.x * k);
        acc1 += truncf(xv.y * k);
        acc2 += truncf(xv.z * k);
        acc3 += truncf(xv.w * k);
    }

    // partials: ws[ic][b][j]
    float* wp = ws + ((size_t)ic * BDIM + b0) * UNITS + j;
    wp[0 * UNITS] = acc0;
    wp[1 * UNITS] = acc1;
    wp[2 * UNITS] = acc2;
    wp[3 * UNITS] = acc3;
}

__global__ __launch_bounds__(256) void reduce_kernel(
    const float* __restrict__ ws, const float* __restrict__ bias,
    float* __restrict__ out)
{
    const int idx = blockIdx.x * 256 + threadIdx.x;  // 16384 float4 groups
    const int j4 = idx & 255;                        // 256 float4 per j-row
    const int b  = idx >> 8;

    const float4* p = (const float4*)ws + (size_t)b * (UNITS / 4) + j4;
    float4 s = make_float4(0.f, 0.f, 0.f, 0.f);
#pragma unroll
    for (int c = 0; c < NCH; ++c) {
        const float4 v = p[(size_t)c * BDIM * (UNITS / 4)];
        s.x += v.x; s.y += v.y; s.z += v.z; s.w += v.w;
    }
    const float4 bv = ((const float4*)bias)[j4];
    s.x = fmaxf(s.x + bv.x, 0.f);
    s.y = fmaxf(s.y + bv.y, 0.f);
    s.z = fmaxf(s.z + bv.z, 0.f);
    s.w = fmaxf(s.w + bv.w, 0.f);
    ((float4*)out)[idx] = s;
}

extern "C" void kernel_launch(void* const* d_in, const int* in_sizes, int n_in,
                              void* d_out, int out_size, void* d_ws, size_t ws_size,
                              hipStream_t stream) {
    const float* x    = (const float*)d_in[0];  // (64, 1024)
    const float* K    = (const float*)d_in[1];  // (1024, 1024)
    const float* bias = (const float*)d_in[2];  // (1024,)
    // d_in[3] = bits (always 8)
    float* out = (float*)d_out;                 // (64, 1024)
    float* ws  = (float*)d_ws;                  // uses NCH*B*UNITS*4 = 2 MB

    partial_kernel<<<512, 256, 0, stream>>>(x, K, ws);
    reduce_kernel<<<64, 256, 0, stream>>>(ws, bias, out);
}